// Round 1
// baseline (184.239 us; speedup 1.0000x reference)
//
#include <hip/hip_runtime.h>

// DCT compression: (32,3,512,512) fp32 -> (32,192,64,64) fp32
// Per 8x8 block: coef[a,u] = sum_{y,x} blk[y,x]*C8[a,y]*C8[u,x]
//   C8[u,y] = cos((u+0.5)*PI*y/8), PI = 3.1415 (module's approximation!)
// norm[a,u] = (a==0||u==0) ? sqrt(2)/8 : 0.25   (NOT separable: [0][0]=sqrt2/8)
// out[b, c*64 + z[a*8+u], hb, wb] = coef[a,u]*norm[a,u] / Qtab[c][z[a*8+u]]
// z = zigzag index matrix (ported verbatim from reference _zigzag, incl. .T)

#define PI_F 3.1415f

// Q=50 -> s=100 -> Q_luma = floor((100*T+50)/100) = T exactly (integers)
__device__ __constant__ int QTAB[2][64] = {
    {16,11,10,16,24,40,51,61,
     12,12,14,19,26,58,60,55,
     14,13,16,24,40,57,69,56,
     14,17,22,29,51,87,80,62,
     18,22,37,56,68,109,103,77,
     24,35,55,64,81,104,113,92,
     49,64,78,87,103,121,120,101,
     72,92,95,98,112,100,103,99},
    {17,18,24,47,99,99,99,99,
     18,21,26,66,99,99,99,99,
     24,26,56,99,99,99,99,99,
     47,66,99,99,99,99,99,99,
     99,99,99,99,99,99,99,99,
     99,99,99,99,99,99,99,99,
     99,99,99,99,99,99,99,99,
     99,99,99,99,99,99,99,99}
};

// Grid: 1536 workgroups of 256 threads.
//   blockIdx.x = bc*16 + hbg;  bc = b*3+c in [0,96);  hbg in [0,16)
//   wave (tid>>6) picks hb = hbg*4 + wave;  lane (tid&63) = wb.
// Each lane: one 8x8 block -> 64 outputs.
__global__ __launch_bounds__(256)
void DCTCompression_25786983645730_kernel(const float* __restrict__ x,
                                          float* __restrict__ out) {
    __shared__ float sC8[64];     // sC8[u*8+y] = cos((u+0.5)*PI*y/8)
    __shared__ float sScale[64];  // sScale[a*8+u] = norm(a,u)/Qtab[c][z]
    __shared__ int   sZoff[64];   // z[a*8+u] * 4096 (output element offset)

    const int tid = threadIdx.x;
    const int idx = blockIdx.x;
    const int hbg = idx & 15;
    const int bc  = idx >> 4;     // b*3 + c
    const int c   = bc % 3;

    if (tid == 0) {
        // faithful port of reference _zigzag(8); p is pre-transpose pattern
        int p[64];
        for (int y = 0; y < 8; ++y)
            for (int xx = (y & 1); xx < 8 - y; xx += 2) {
                int v = xx + y + 1;
                p[y * 8 + xx] = v * (v + 1) / 2 - xx - 1;
            }
        for (int y = 0; y < 8; ++y)
            for (int xx = ((y + 1) & 1); xx < 8 - y; xx += 2) {
                int v = xx + y + 1;
                p[y * 8 + xx] = v * (v + 1) / 2 - y - 1;
            }
        for (int y = 7; y >= 0; --y)
            for (int xx = 7; xx >= 8 - y; --xx)
                p[y * 8 + xx] = 63 - p[(7 - y) * 8 + (7 - xx)];
        // z[a*8+u] = p.T[a][u] = p[u*8+a]
        const int* qt = QTAB[(c == 0) ? 0 : 1];
        for (int i = 0; i < 64; ++i) {
            int a = i >> 3, u = i & 7;
            int zi = p[u * 8 + a];
            sZoff[i] = zi << 12;  // * 64*64
            float nrm = (a == 0 || u == 0) ? 0.17677669529663687f : 0.25f;
            sScale[i] = nrm / (float)qt[zi];
        }
    }
    if (tid < 64) {
        int u = tid >> 3, y = tid & 7;
        sC8[tid] = cosf(((float)u + 0.5f) * PI_F * ((float)y * 0.125f));
    }
    __syncthreads();

    const int wave = tid >> 6;
    const int wb   = tid & 63;
    const int hb   = hbg * 4 + wave;

    const float* xb = x + ((size_t)bc * 512 + (size_t)hb * 8) * 512 + wb * 8;
    float* ob = out + (size_t)bc * 64 * 4096 + hb * 64 + wb;

    // ---- load 8x8 block: 16 independent float4 loads (coalesced) ----
    float4 r[8][2];
#pragma unroll
    for (int y = 0; y < 8; ++y) {
        r[y][0] = *reinterpret_cast<const float4*>(xb + y * 512);
        r[y][1] = *reinterpret_cast<const float4*>(xb + y * 512 + 4);
    }

    // ---- pass 1: tmp[a][x] = sum_y C8[a][y] * blk[y][x] ----
    float tmp[8][8];
#pragma unroll
    for (int a = 0; a < 8; ++a)
#pragma unroll
        for (int xx = 0; xx < 8; ++xx) tmp[a][xx] = 0.0f;

#pragma unroll
    for (int y = 0; y < 8; ++y) {
        float row[8] = {r[y][0].x, r[y][0].y, r[y][0].z, r[y][0].w,
                        r[y][1].x, r[y][1].y, r[y][1].z, r[y][1].w};
#pragma unroll
        for (int a = 0; a < 8; ++a) {
            float cv = sC8[a * 8 + y];
#pragma unroll
            for (int xx = 0; xx < 8; ++xx)
                tmp[a][xx] = fmaf(cv, row[xx], tmp[a][xx]);
        }
    }

    // ---- pass 2: coef[a][u] = sum_x tmp[a][x] * C8[u][x]; scale + scatter ----
#pragma unroll
    for (int a = 0; a < 8; ++a) {
#pragma unroll
        for (int u = 0; u < 8; ++u) {
            float acc = 0.0f;
#pragma unroll
            for (int xx = 0; xx < 8; ++xx)
                acc = fmaf(tmp[a][xx], sC8[u * 8 + xx], acc);
            int j = a * 8 + u;
            ob[sZoff[j]] = acc * sScale[j];  // coalesced across wave (wb contig)
        }
    }
}

extern "C" void kernel_launch(void* const* d_in, const int* in_sizes, int n_in,
                              void* d_out, int out_size, void* d_ws, size_t ws_size,
                              hipStream_t stream) {
    const float* x = (const float*)d_in[0];
    float* out = (float*)d_out;
    // B*C*(H/8/4) = 32*3*16 = 1536 workgroups, 256 threads each
    DCTCompression_25786983645730_kernel<<<dim3(1536), dim3(256), 0, stream>>>(x, out);
}